// Round 6
// baseline (147.322 us; speedup 1.0000x reference)
//
#include <hip/hip_runtime.h>

typedef short bf16x8 __attribute__((ext_vector_type(8)));
typedef float f32x4 __attribute__((ext_vector_type(4)));

#define LN_EPS 1e-5f
#define SLOPE 0.2f

__device__ __forceinline__ float bf2f(unsigned short s){
  return __uint_as_float(((unsigned)s) << 16);
}
__device__ __forceinline__ unsigned short f2bf(float f){
  unsigned u = __float_as_uint(f);
  u += 0x7fffu + ((u >> 16) & 1u);   // round-to-nearest-even
  return (unsigned short)(u >> 16);
}

// Verified W image (rounds 1/4):
// element ((s*4+g)*512 + c)*8 + j  =  W[k = s*32+g*8+j][c]   (c<256: W_l, else W_r)
__global__ void wconv_kernel(const float* __restrict__ Wl,
                             const float* __restrict__ Wr,
                             unsigned short* __restrict__ wbf){
  int idx = blockIdx.x * 256 + threadIdx.x;   // 0..131071
  int j = idx & 7;
  int c = (idx >> 3) & 511;
  int g = (idx >> 12) & 3;
  int s = idx >> 14;
  int k = s * 32 + g * 8 + j;
  float v = (c < 256) ? Wl[k * 256 + c] : Wr[k * 256 + (c - 256)];
  wbf[idx] = f2bf(v);
}

// Round-5 text; ONLY change: __launch_bounds__(512,4) -> (512,2).
// minwaves=4 correlates perfectly with all 3 correctness failures (VGPR cap 128
// forces accumulator spill/remat — suspected codegen hazard). Occupancy comes
// from the 512-thread block instead: 64KB LDS -> 2 blocks/CU = 16 waves/CU.
template<bool USE_WS>
__global__ __launch_bounds__(512, 2)
void gat_fused(const float* __restrict__ hin, const float* __restrict__ ebias,
               const float* __restrict__ Wl, const float* __restrict__ Wr,
               const float* __restrict__ avec, const float* __restrict__ gmw,
               const float* __restrict__ btw, const unsigned short* __restrict__ wbf,
               float* __restrict__ out){
  // GEMM phase: h tile [64][256] bf16 (32KB, XOR-swizzled) in lds[0..16384)
  // attn phase: g tile [64][512] bf16 (64KB) overlays all of lds (after barrier)
  __shared__ __align__(16) unsigned short lds[32768];
  __shared__ float a_s[256];
  __shared__ float eb_s[16];
  const int t = threadIdx.x;
  const int lane = t & 63;
  const int w = t >> 6;                 // 0..7
  const int b0 = blockIdx.x * 16;

  if (t < 256) a_s[t] = avec[t];
  if (t < 16) eb_s[t] = ebias[t];

  // ---- stage h tile (64 rows x 256 k) f32->bf16, XOR-swizzled by row&7 (16B units)
  {
    const float* hb = hin + (size_t)b0 * 1024;
    #pragma unroll
    for (int it = 0; it < 4; ++it){
      int q = it * 512 + t;             // 16B-chunk id, 2048 total
      int row = q >> 5;
      int c = q & 31;
      const float* src = hb + row * 256 + c * 8;
      float4 f0 = *(const float4*)src;
      float4 f1 = *(const float4*)(src + 4);
      bf16x8 v;
      v[0]=f2bf(f0.x); v[1]=f2bf(f0.y); v[2]=f2bf(f0.z); v[3]=f2bf(f0.w);
      v[4]=f2bf(f1.x); v[5]=f2bf(f1.y); v[6]=f2bf(f1.z); v[7]=f2bf(f1.w);
      *(bf16x8*)&lds[row * 256 + ((c ^ (row & 7)) << 3)] = v;
    }
  }
  __syncthreads();

  f32x4 acc[4][4];
  #pragma unroll
  for (int m = 0; m < 4; ++m)
    #pragma unroll
    for (int c = 0; c < 4; ++c)
      acc[m][c] = (f32x4){0.f, 0.f, 0.f, 0.f};

  const int g = lane >> 4;
  const int ln = lane & 15;

  for (int step = 0; step < 8; ++step){
    // fragments: A/B both use k-slot mapping k' = g*8 + j (consistent => correct)
    bf16x8 af[4], bfr[4];
    #pragma unroll
    for (int m = 0; m < 4; ++m){
      int row = m * 16 + ln;
      int chunk = step * 4 + g;
      af[m] = *(const bf16x8*)&lds[row * 256 + ((chunk ^ (row & 7)) << 3)];
    }
    if constexpr (USE_WS){
      const unsigned short* wp = wbf + (size_t)step * 16384 + (size_t)g * 4096
                               + (size_t)(w * 64 + ln) * 8;
      #pragma unroll
      for (int c = 0; c < 4; ++c)
        bfr[c] = *(const bf16x8*)(wp + c * 128);
    } else {
      #pragma unroll
      for (int c = 0; c < 4; ++c){
        int col = w * 64 + c * 16 + ln;
        const float* sp = (col < 256) ? (Wl + col) : (Wr + (col - 256));
        #pragma unroll
        for (int j = 0; j < 8; ++j)
          bfr[c][j] = f2bf(sp[(step * 32 + g * 8 + j) * 256]);
      }
    }
    #pragma unroll
    for (int m = 0; m < 4; ++m)
      #pragma unroll
      for (int c = 0; c < 4; ++c)
        acc[m][c] = __builtin_amdgcn_mfma_f32_16x16x32_bf16(af[m], bfr[c], acc[m][c], 0, 0, 0);
  }
  __syncthreads();

  // ---- write g tile [64][512] bf16 into LDS (C layout: row=(lane>>4)*4+j, col=lane&15)
  #pragma unroll
  for (int m = 0; m < 4; ++m)
    #pragma unroll
    for (int c = 0; c < 4; ++c){
      int col = w * 64 + c * 16 + ln;
      #pragma unroll
      for (int j = 0; j < 4; ++j){
        int row = m * 16 + g * 4 + j;
        lds[row * 512 + col] = f2bf(acc[m][c][j]);
      }
    }
  __syncthreads();

  // ---- attention + LN: wave w handles local batches w*2 .. w*2+1, sequentially
  const int i_ = lane >> 4;          // e-phase roles: lane = i*16 + j*4 + h
  const int j_ = (lane >> 2) & 3;
  const int h_ = lane & 3;
  const int c0 = (lane & 15) * 16;   // h'-phase: lane owns row i_, cols c0..c0+15
  const int h2 = (lane & 15) >> 2;   // head of that col range

  float4 gmv[4], btv[4];
  #pragma unroll
  for (int q = 0; q < 4; ++q){
    gmv[q] = *(const float4*)(gmw + c0 + q * 4);
    btv[q] = *(const float4*)(btw + c0 + q * 4);
  }

  for (int p = 0; p < 2; ++p){
    int bb = w * 2 + p;
    // e[i][j][h] = sum_d leaky(g_l[i][h*64+d] + g_r[j][h*64+d]) * a[h][d] + eb[i][j]
    float e = 0.f;
    {
      const int rl = (bb * 4 + i_) * 512 + h_ * 64;
      const int rr = (bb * 4 + j_) * 512 + 256 + h_ * 64;
      #pragma unroll
      for (int d8 = 0; d8 < 8; ++d8){
        bf16x8 gl = *(const bf16x8*)&lds[rl + d8 * 8];
        bf16x8 gr = *(const bf16x8*)&lds[rr + d8 * 8];
        #pragma unroll
        for (int u = 0; u < 8; ++u){
          float x = bf2f((unsigned short)gl[u]) + bf2f((unsigned short)gr[u]);
          x = (x >= 0.f) ? x : SLOPE * x;
          e = fmaf(x, a_s[h_ * 64 + d8 * 8 + u], e);
        }
      }
      e += eb_s[i_ * 4 + j_];
    }
    // softmax over j (j lives in lane bits 2..3)
    float mx = fmaxf(e, __shfl_xor(e, 4));
    mx = fmaxf(mx, __shfl_xor(mx, 8));
    float pr = __expf(e - mx);
    float sm = pr + __shfl_xor(pr, 4);
    sm += __shfl_xor(sm, 8);
    float alpha = pr / sm;

    // h'[i][c] = sum_j alpha[i][j][h(c)] * g_r[j][c]
    float hp[16];
    #pragma unroll
    for (int u = 0; u < 16; ++u) hp[u] = 0.f;
    #pragma unroll
    for (int j = 0; j < 4; ++j){
      float aj = __shfl(alpha, (lane & 48) + j * 4 + h2);
      const int rb = (bb * 4 + j) * 512 + 256 + c0;
      bf16x8 v0 = *(const bf16x8*)&lds[rb];
      bf16x8 v1 = *(const bf16x8*)&lds[rb + 8];
      #pragma unroll
      for (int u = 0; u < 8; ++u){
        hp[u]     = fmaf(aj, bf2f((unsigned short)v0[u]), hp[u]);
        hp[u + 8] = fmaf(aj, bf2f((unsigned short)v1[u]), hp[u + 8]);
      }
    }
    // LayerNorm over the 256 cols of row i_ (16 lanes share a row: xor 1,2,4,8)
    float s1 = 0.f, s2 = 0.f;
    #pragma unroll
    for (int u = 0; u < 16; ++u){ s1 += hp[u]; s2 = fmaf(hp[u], hp[u], s2); }
    #pragma unroll
    for (int mask = 1; mask <= 8; mask <<= 1){
      s1 += __shfl_xor(s1, mask);
      s2 += __shfl_xor(s2, mask);
    }
    float mu = s1 * (1.f / 256.f);
    float var = s2 * (1.f / 256.f) - mu * mu;
    float inv = rsqrtf(var + LN_EPS);

    float* op = out + (((size_t)(b0 + bb)) * 4 + i_) * 256 + c0;
    #pragma unroll
    for (int q = 0; q < 4; ++q){
      float4 o;
      const float* gq = (const float*)&gmv[q];
      const float* bq = (const float*)&btv[q];
      o.x = fmaf((hp[q*4+0] - mu) * inv, gq[0], bq[0]);
      o.y = fmaf((hp[q*4+1] - mu) * inv, gq[1], bq[1]);
      o.z = fmaf((hp[q*4+2] - mu) * inv, gq[2], bq[2]);
      o.w = fmaf((hp[q*4+3] - mu) * inv, gq[3], bq[3]);
      *(float4*)(op + q * 4) = o;
    }
  }
}

extern "C" void kernel_launch(void* const* d_in, const int* in_sizes, int n_in,
                              void* d_out, int out_size, void* d_ws, size_t ws_size,
                              hipStream_t stream){
  const float* h  = (const float*)d_in[0];
  const float* eb = (const float*)d_in[1];
  const float* Wl = (const float*)d_in[2];
  const float* Wr = (const float*)d_in[3];
  const float* a  = (const float*)d_in[4];
  const float* gm = (const float*)d_in[5];
  const float* bt = (const float*)d_in[6];
  float* out = (float*)d_out;
  (void)n_in; (void)out_size;

  int B = in_sizes[0] / 1024;        // (B, 4, 256) f32
  int nblk = B / 16;

  if (ws_size >= 262144){
    unsigned short* wbf = (unsigned short*)d_ws;
    wconv_kernel<<<512, 256, 0, stream>>>(Wl, Wr, wbf);
    gat_fused<true><<<nblk, 512, 0, stream>>>(h, eb, Wl, Wr, a, gm, bt, wbf, out);
  } else {
    gat_fused<false><<<nblk, 512, 0, stream>>>(h, eb, Wl, Wr, a, gm, bt, nullptr, out);
  }
}

// Round 7
// 135.668 us; speedup vs baseline: 1.0859x; 1.0859x over previous
//
#include <hip/hip_runtime.h>

typedef short bf16x8 __attribute__((ext_vector_type(8)));
typedef float f32x4 __attribute__((ext_vector_type(4)));

#define LN_EPS 1e-5f
#define SLOPE 0.2f

__device__ __forceinline__ float bf2f(unsigned short s){
  return __uint_as_float(((unsigned)s) << 16);
}
__device__ __forceinline__ unsigned short f2bf(float f){
  unsigned u = __float_as_uint(f);
  u += 0x7fffu + ((u >> 16) & 1u);   // round-to-nearest-even
  return (unsigned short)(u >> 16);
}

// Verified W image (rounds 1/4/6, scalar):
// element ((s*4+g)*512 + c)*8 + j  =  W[k = s*32+g*8+j][c]   (c<256: W_l, else W_r)
__global__ void wconv_kernel(const float* __restrict__ Wl,
                             const float* __restrict__ Wr,
                             unsigned short* __restrict__ wbf){
  int idx = blockIdx.x * 256 + threadIdx.x;   // 0..131071
  int j = idx & 7;
  int c = (idx >> 3) & 511;
  int g = (idx >> 12) & 3;
  int s = idx >> 14;
  int k = s * 32 + g * 8 + j;
  float v = (c < 256) ? Wl[k * 256 + c] : Wr[k * 256 + (c - 256)];
  wbf[idx] = f2bf(v);
}

// g-tile layout (attn phase): shorts, addr = row*584 + head*72 + d
//   row 0..31 (batch*4+node), head 0..7 (0-3 = g_l heads, 4-7 = g_r heads), d 0..63.
//   Strides: row 1168 B, head 144 B -> e-phase reads spread (chunk mod 8 = i+h, <=4-way
//   vs 16-way in the linear [64][512] layout).
// h-tile (GEMM phase) overlays first 16 KB: shorts, row*256 + ((chunk^(row&7))<<3).
#define ST_ROW 584
#define ST_H 72

// NOTE: minwaves/EU >= 4 in __launch_bounds__ MISCOMPILES this kernel
// (confirmed by R5->R6 single-variable test). Keep minwaves = 2.
template<bool USE_WS>
__global__ __launch_bounds__(256, 2)
void gat_fused(const float* __restrict__ hin, const float* __restrict__ ebias,
               const float* __restrict__ Wl, const float* __restrict__ Wr,
               const float* __restrict__ avec, const float* __restrict__ gmw,
               const float* __restrict__ btw, const unsigned short* __restrict__ wbf,
               float* __restrict__ out){
  __shared__ __align__(16) unsigned short gt[18688];   // 37376 B
  __shared__ float a_s[4 * 72];
  __shared__ float eb_s[16];

  const int t = threadIdx.x;
  const int lane = t & 63;
  const int w = t >> 6;
  const int b0 = blockIdx.x * 8;
  const int g = lane >> 4;
  const int ln = lane & 15;

  a_s[(t >> 6) * 72 + (t & 63)] = avec[t];
  if (t < 16) eb_s[t] = ebias[t];

  // ---- stage h tile (32 rows x 256 k) f32->bf16, chunk-XOR swizzle (verified)
  {
    const float* hb = hin + (size_t)b0 * 1024;
    #pragma unroll
    for (int it = 0; it < 4; ++it){
      int q = it * 256 + t;              // 16B-chunk id, 1024 total
      int row = q >> 5;
      int c = q & 31;
      const float* src = hb + row * 256 + c * 8;
      float4 f0 = *(const float4*)src;
      float4 f1 = *(const float4*)(src + 4);
      bf16x8 v;
      v[0]=(short)f2bf(f0.x); v[1]=(short)f2bf(f0.y); v[2]=(short)f2bf(f0.z); v[3]=(short)f2bf(f0.w);
      v[4]=(short)f2bf(f1.x); v[5]=(short)f2bf(f1.y); v[6]=(short)f2bf(f1.z); v[7]=(short)f2bf(f1.w);
      *(bf16x8*)&gt[row * 256 + ((c ^ (row & 7)) << 3)] = v;
    }
  }
  __syncthreads();

  f32x4 acc[2][8];                        // [rowblock m][colblock c]
  #pragma unroll
  for (int m = 0; m < 2; ++m)
    #pragma unroll
    for (int c = 0; c < 8; ++c)
      acc[m][c] = (f32x4){0.f, 0.f, 0.f, 0.f};

  // ---- barrier-free K loop: A = h frags from LDS, B = W frags from L2 (verified R4)
  #pragma unroll
  for (int step = 0; step < 8; ++step){
    bf16x8 af[2];
    #pragma unroll
    for (int m = 0; m < 2; ++m){
      int row = m * 16 + ln;
      int chunk = step * 4 + g;
      af[m] = *(const bf16x8*)&gt[row * 256 + ((chunk ^ (row & 7)) << 3)];
    }
    bf16x8 bfr[8];
    if constexpr (USE_WS){
      const unsigned short* wp = wbf + (size_t)step * 16384 + (size_t)g * 4096
                               + (size_t)(w * 128 + ln) * 8;
      #pragma unroll
      for (int c = 0; c < 8; ++c)
        bfr[c] = *(const bf16x8*)(wp + c * 128);
    } else {
      #pragma unroll
      for (int c = 0; c < 8; ++c){
        int col = w * 128 + c * 16 + ln;
        const float* sp = (col < 256) ? (Wl + col) : (Wr + (col - 256));
        #pragma unroll
        for (int j = 0; j < 8; ++j)
          bfr[c][j] = (short)f2bf(sp[(step * 32 + g * 8 + j) * 256]);
      }
    }
    #pragma unroll
    for (int m = 0; m < 2; ++m)
      #pragma unroll
      for (int c = 0; c < 8; ++c)
        acc[m][c] = __builtin_amdgcn_mfma_f32_16x16x32_bf16(af[m], bfr[c], acc[m][c], 0, 0, 0);
  }
  __syncthreads();                        // h-tile reads done before g-tile overlay

  // ---- write g tile: verified C/D mapping: row = m*16+g*4+j, col = w*128+c*16+ln
  #pragma unroll
  for (int m = 0; m < 2; ++m)
    #pragma unroll
    for (int c = 0; c < 8; ++c){
      int col = w * 128 + c * 16 + ln;
      int base = (col >> 6) * ST_H + (col & 63);
      #pragma unroll
      for (int j = 0; j < 4; ++j){
        int row = m * 16 + g * 4 + j;
        gt[row * ST_ROW + base] = (unsigned short)f2bf(acc[m][c][j]);
      }
    }
  __syncthreads();

  // ---- attention + LN (round-1 verified logic; g-tile addressing padded)
  const int i_ = lane >> 4;               // e-phase roles: lane = i*16 + j*4 + h
  const int j_ = (lane >> 2) & 3;
  const int h_ = lane & 3;
  const int c0 = (lane & 15) * 16;        // h'-phase: lane owns row i_, cols c0..c0+15
  const int h2 = (lane & 15) >> 2;        // head of that col range

  float4 gmv[4], btv[4];
  #pragma unroll
  for (int q = 0; q < 4; ++q){
    gmv[q] = *(const float4*)(gmw + c0 + q * 4);
    btv[q] = *(const float4*)(btw + c0 + q * 4);
  }

  for (int p = 0; p < 2; ++p){
    int bb = w * 2 + p;
    int ri = bb * 4 + i_;
    int rj = bb * 4 + j_;
    // e[i][j][h] = sum_d leaky(g_l[i][h,d] + g_r[j][h,d]) * a[h][d] + eb[i][j]
    float e = 0.f;
    #pragma unroll
    for (int d8 = 0; d8 < 8; ++d8){
      bf16x8 gl = *(const bf16x8*)&gt[ri * ST_ROW + h_ * ST_H + d8 * 8];
      bf16x8 gr = *(const bf16x8*)&gt[rj * ST_ROW + (4 + h_) * ST_H + d8 * 8];
      #pragma unroll
      for (int u = 0; u < 8; ++u){
        float x = bf2f((unsigned short)gl[u]) + bf2f((unsigned short)gr[u]);
        x = (x >= 0.f) ? x : SLOPE * x;
        e = fmaf(x, a_s[h_ * 72 + d8 * 8 + u], e);
      }
    }
    e += eb_s[i_ * 4 + j_];
    // softmax over j (lane bits 2..3)
    float mx = fmaxf(e, __shfl_xor(e, 4));
    mx = fmaxf(mx, __shfl_xor(mx, 8));
    float pr = __expf(e - mx);
    float sm = pr + __shfl_xor(pr, 4);
    sm += __shfl_xor(sm, 8);
    float alpha = pr / sm;

    // h'[i][c0..c0+15] = sum_j alpha[i][j][h2] * g_r[j][c0..c0+15]
    float hp[16];
    #pragma unroll
    for (int u = 0; u < 16; ++u) hp[u] = 0.f;
    #pragma unroll
    for (int j = 0; j < 4; ++j){
      float aj = __shfl(alpha, (lane & 48) + j * 4 + h2);
      int rr = bb * 4 + j;
      const unsigned short* vp = &gt[rr * ST_ROW + (4 + ((lane & 15) >> 2)) * ST_H
                                     + ((lane & 3) << 4)];
      bf16x8 v0 = *(const bf16x8*)vp;
      bf16x8 v1 = *(const bf16x8*)(vp + 8);
      #pragma unroll
      for (int u = 0; u < 8; ++u){
        hp[u]     = fmaf(aj, bf2f((unsigned short)v0[u]), hp[u]);
        hp[u + 8] = fmaf(aj, bf2f((unsigned short)v1[u]), hp[u + 8]);
      }
    }
    // LayerNorm over 256 cols of row i_ (16 lanes share a row)
    float s1 = 0.f, s2 = 0.f;
    #pragma unroll
    for (int u = 0; u < 16; ++u){ s1 += hp[u]; s2 = fmaf(hp[u], hp[u], s2); }
    #pragma unroll
    for (int mask = 1; mask <= 8; mask <<= 1){
      s1 += __shfl_xor(s1, mask);
      s2 += __shfl_xor(s2, mask);
    }
    float mu = s1 * (1.f / 256.f);
    float var = s2 * (1.f / 256.f) - mu * mu;
    float inv = rsqrtf(var + LN_EPS);

    float* op = out + (((size_t)(b0 + bb)) * 4 + i_) * 256 + c0;
    #pragma unroll
    for (int q = 0; q < 4; ++q){
      const float* gq = (const float*)&gmv[q];
      const float* bq = (const float*)&btv[q];
      float4 o;
      o.x = fmaf((hp[q*4+0] - mu) * inv, gq[0], bq[0]);
      o.y = fmaf((hp[q*4+1] - mu) * inv, gq[1], bq[1]);
      o.z = fmaf((hp[q*4+2] - mu) * inv, gq[2], bq[2]);
      o.w = fmaf((hp[q*4+3] - mu) * inv, gq[3], bq[3]);
      *(float4*)(op + q * 4) = o;
    }
  }
}

extern "C" void kernel_launch(void* const* d_in, const int* in_sizes, int n_in,
                              void* d_out, int out_size, void* d_ws, size_t ws_size,
                              hipStream_t stream){
  const float* h  = (const float*)d_in[0];
  const float* eb = (const float*)d_in[1];
  const float* Wl = (const float*)d_in[2];
  const float* Wr = (const float*)d_in[3];
  const float* a  = (const float*)d_in[4];
  const float* gm = (const float*)d_in[5];
  const float* bt = (const float*)d_in[6];
  float* out = (float*)d_out;
  (void)n_in; (void)out_size;

  int B = in_sizes[0] / 1024;            // (B, 4, 256) f32
  int nblk = B / 8;

  if (ws_size >= 262144){
    unsigned short* wbf = (unsigned short*)d_ws;
    wconv_kernel<<<512, 256, 0, stream>>>(Wl, Wr, wbf);
    gat_fused<true><<<nblk, 256, 0, stream>>>(h, eb, Wl, Wr, a, gm, bt, wbf, out);
  } else {
    gat_fused<false><<<nblk, 256, 0, stream>>>(h, eb, Wl, Wr, a, gm, bt, nullptr, out);
  }
}

// Round 9
// 109.077 us; speedup vs baseline: 1.3506x; 1.2438x over previous
//
#include <hip/hip_runtime.h>

typedef short bf16x8 __attribute__((ext_vector_type(8)));
typedef float f32x4 __attribute__((ext_vector_type(4)));

#define LN_EPS 1e-5f
#define SLOPE 0.2f

__device__ __forceinline__ float bf2f(unsigned short s){
  return __uint_as_float(((unsigned)s) << 16);
}
__device__ __forceinline__ unsigned short f2bf(float f){
  unsigned u = __float_as_uint(f);
  u += 0x7fffu + ((u >> 16) & 1u);   // round-to-nearest-even
  return (unsigned short)(u >> 16);
}

// Verified W image (rounds 1/4/6/7, scalar):
// element ((s*4+g)*512 + c)*8 + j  =  W[k = s*32+g*8+j][c]   (c<256: W_l, else W_r)
__global__ void wconv_kernel(const float* __restrict__ Wl,
                             const float* __restrict__ Wr,
                             unsigned short* __restrict__ wbf){
  int idx = blockIdx.x * 256 + threadIdx.x;   // 0..131071
  int j = idx & 7;
  int c = (idx >> 3) & 511;
  int g = (idx >> 12) & 3;
  int s = idx >> 14;
  int k = s * 32 + g * 8 + j;
  float v = (c < 256) ? Wl[k * 256 + c] : Wr[k * 256 + (c - 256)];
  wbf[idx] = f2bf(v);
}

// Register-attention v2: wave w owns HEAD w. Verified C/D mapping (row=m*16+g*4+slot)
// puts, for batch bb=m*4+g, node n in f32-slot n: gl[n,d=c*16+ln]=acc[m][c][n],
// gr[n,d]=acc[m][c+4][n]. e/softmax/PV all in registers; hp stays in f32 REGISTERS
// across the barrier (no LDS round-trip, no bf16 rounding). Only LN partials
// (s1,s2 per row x head) go through LDS.
// NOTE: minwaves/EU >= 4 in __launch_bounds__ MISCOMPILES (R5->R6 test). Keep 2.
template<bool USE_WS>
__global__ __launch_bounds__(256, 2)
void gat_fused(const float* __restrict__ hin, const float* __restrict__ ebias,
               const float* __restrict__ Wl, const float* __restrict__ Wr,
               const float* __restrict__ avec, const float* __restrict__ gmw,
               const float* __restrict__ btw, const unsigned short* __restrict__ wbf,
               float* __restrict__ out){
  __shared__ __align__(16) unsigned short uni[16384];   // h-tile only, 32KB
  __shared__ float red1[256], red2[256];                // [row][wave] LN partials

  const int t = threadIdx.x;
  const int lane = t & 63;
  const int w = t >> 6;
  const int b0 = blockIdx.x * 16;
  const int g = lane >> 4;
  const int ln = lane & 15;

  // per-lane constants (registers)
  float av[4], gmr[4], btr[4];
  #pragma unroll
  for (int c = 0; c < 4; ++c){
    av[c]  = avec[w * 64 + c * 16 + ln];
    gmr[c] = gmw [w * 64 + c * 16 + ln];
    btr[c] = btw [w * 64 + c * 16 + ln];
  }
  float ebv[16];
  #pragma unroll
  for (int q = 0; q < 16; ++q) ebv[q] = ebias[q];

  // ---- stage h tile (64 rows x 256 k) f32->bf16, XOR-swizzled (verified R4)
  {
    const float* hb = hin + (size_t)b0 * 1024;
    #pragma unroll
    for (int it = 0; it < 8; ++it){
      int q = it * 256 + t;              // 16B-chunk id, 2048 total
      int row = q >> 5;
      int c = q & 31;
      const float* src = hb + row * 256 + c * 8;
      float4 f0 = *(const float4*)src;
      float4 f1 = *(const float4*)(src + 4);
      bf16x8 v;
      v[0]=(short)f2bf(f0.x); v[1]=(short)f2bf(f0.y); v[2]=(short)f2bf(f0.z); v[3]=(short)f2bf(f0.w);
      v[4]=(short)f2bf(f1.x); v[5]=(short)f2bf(f1.y); v[6]=(short)f2bf(f1.z); v[7]=(short)f2bf(f1.w);
      *(bf16x8*)&uni[row * 256 + ((c ^ (row & 7)) << 3)] = v;
    }
  }
  __syncthreads();

  f32x4 acc[4][8];
  #pragma unroll
  for (int m = 0; m < 4; ++m)
    #pragma unroll
    for (int c = 0; c < 8; ++c)
      acc[m][c] = (f32x4){0.f, 0.f, 0.f, 0.f};

  // ---- barrier-free K loop: A = h frags from LDS, B = W frags from L2 (verified R4)
  for (int step = 0; step < 8; ++step){
    bf16x8 af[4], bfr[8];
    #pragma unroll
    for (int m = 0; m < 4; ++m){
      int row = m * 16 + ln;
      int chunk = step * 4 + g;
      af[m] = *(const bf16x8*)&uni[row * 256 + ((chunk ^ (row & 7)) << 3)];
    }
    if constexpr (USE_WS){
      const unsigned short* wp = wbf + (size_t)step * 16384 + (size_t)g * 4096
                               + (size_t)(w * 64 + ln) * 8;
      #pragma unroll
      for (int c = 0; c < 4; ++c){
        bfr[c]     = *(const bf16x8*)(wp + c * 128);          // gl col w*64+c*16+ln
        bfr[c + 4] = *(const bf16x8*)(wp + 2048 + c * 128);   // gr col 256+w*64+c*16+ln
      }
    } else {
      #pragma unroll
      for (int c = 0; c < 4; ++c){
        int col = w * 64 + c * 16 + ln;
        #pragma unroll
        for (int j = 0; j < 8; ++j){
          bfr[c][j]     = (short)f2bf(Wl[(step * 32 + g * 8 + j) * 256 + col]);
          bfr[c + 4][j] = (short)f2bf(Wr[(step * 32 + g * 8 + j) * 256 + col]);
        }
      }
    }
    #pragma unroll
    for (int m = 0; m < 4; ++m)
      #pragma unroll
      for (int c = 0; c < 8; ++c)
        acc[m][c] = __builtin_amdgcn_mfma_f32_16x16x32_bf16(af[m], bfr[c], acc[m][c], 0, 0, 0);
  }
  __syncthreads();        // all LDS h-tile reads done; uni never touched again

  // ---- attention fully in registers; hp kept in f32 regs (static indices only)
  float hp[4][4][4];      // [m][node i][c-chunk]
  #pragma unroll
  for (int m = 0; m < 4; ++m){
    // e[i*4+j] for head w, batch bb = m*4+g (per lane-group)
    float e[16];
    #pragma unroll
    for (int q = 0; q < 16; ++q) e[q] = 0.f;
    #pragma unroll
    for (int c = 0; c < 4; ++c){
      f32x4 GL = acc[m][c];
      f32x4 GR = acc[m][c + 4];
      #pragma unroll
      for (int i = 0; i < 4; ++i)
        #pragma unroll
        for (int j = 0; j < 4; ++j){
          float x = GL[i] + GR[j];
          x = fmaxf(x, SLOPE * x);        // leaky_relu
          e[i * 4 + j] = fmaf(x, av[c], e[i * 4 + j]);
        }
    }
    // reduce d-partials across the 16-lane group
    #pragma unroll
    for (int mask = 1; mask <= 8; mask <<= 1)
      #pragma unroll
      for (int q = 0; q < 16; ++q)
        e[q] += __shfl_xor(e[q], mask);
    #pragma unroll
    for (int q = 0; q < 16; ++q) e[q] += ebv[q];
    // softmax over j (alpha back into e[])
    #pragma unroll
    for (int i = 0; i < 4; ++i){
      float mx = fmaxf(fmaxf(e[i*4+0], e[i*4+1]), fmaxf(e[i*4+2], e[i*4+3]));
      float p0 = __expf(e[i*4+0] - mx);
      float p1 = __expf(e[i*4+1] - mx);
      float p2 = __expf(e[i*4+2] - mx);
      float p3 = __expf(e[i*4+3] - mx);
      float rs = 1.f / (p0 + p1 + p2 + p3);
      e[i*4+0] = p0 * rs; e[i*4+1] = p1 * rs; e[i*4+2] = p2 * rs; e[i*4+3] = p3 * rs;
    }
    // PV in registers + LN partial export (2 scalars per row x head)
    #pragma unroll
    for (int i = 0; i < 4; ++i){
      #pragma unroll
      for (int c = 0; c < 4; ++c){
        f32x4 GR = acc[m][c + 4];
        float v = e[i*4+0] * GR[0];
        v = fmaf(e[i*4+1], GR[1], v);
        v = fmaf(e[i*4+2], GR[2], v);
        v = fmaf(e[i*4+3], GR[3], v);
        hp[m][i][c] = v;
      }
      float s1 = hp[m][i][0] + hp[m][i][1] + hp[m][i][2] + hp[m][i][3];
      float s2 = fmaf(hp[m][i][0], hp[m][i][0],
                 fmaf(hp[m][i][1], hp[m][i][1],
                 fmaf(hp[m][i][2], hp[m][i][2], hp[m][i][3] * hp[m][i][3])));
      #pragma unroll
      for (int mask = 1; mask <= 8; mask <<= 1){
        s1 += __shfl_xor(s1, mask);
        s2 += __shfl_xor(s2, mask);
      }
      int r = (m * 4 + g) * 4 + i;
      if (ln == 0){ red1[r * 4 + w] = s1; red2[r * 4 + w] = s2; }
    }
  }
  __syncthreads();

  // ---- epilogue: combine 4 head-partials, normalize own hp, coalesced stores
  #pragma unroll
  for (int m = 0; m < 4; ++m)
    #pragma unroll
    for (int i = 0; i < 4; ++i){
      int r = (m * 4 + g) * 4 + i;
      float s1 = (red1[r*4+0] + red1[r*4+1]) + (red1[r*4+2] + red1[r*4+3]);
      float s2 = (red2[r*4+0] + red2[r*4+1]) + (red2[r*4+2] + red2[r*4+3]);
      float mu = s1 * (1.f / 256.f);
      float var = s2 * (1.f / 256.f) - mu * mu;
      float inv = rsqrtf(var + LN_EPS);
      float* op = out + ((size_t)b0 * 4 + r) * 256 + w * 64 + ln;
      #pragma unroll
      for (int c = 0; c < 4; ++c)
        op[c * 16] = fmaf((hp[m][i][c] - mu) * inv, gmr[c], btr[c]);
    }
}

extern "C" void kernel_launch(void* const* d_in, const int* in_sizes, int n_in,
                              void* d_out, int out_size, void* d_ws, size_t ws_size,
                              hipStream_t stream){
  const float* h  = (const float*)d_in[0];
  const float* eb = (const float*)d_in[1];
  const float* Wl = (const float*)d_in[2];
  const float* Wr = (const float*)d_in[3];
  const float* a  = (const float*)d_in[4];
  const float* gm = (const float*)d_in[5];
  const float* bt = (const float*)d_in[6];
  float* out = (float*)d_out;
  (void)n_in; (void)out_size;

  int B = in_sizes[0] / 1024;        // (B, 4, 256) f32
  int nblk = B / 16;

  if (ws_size >= 262144){
    unsigned short* wbf = (unsigned short*)d_ws;
    wconv_kernel<<<512, 256, 0, stream>>>(Wl, Wr, wbf);
    gat_fused<true><<<nblk, 256, 0, stream>>>(h, eb, Wl, Wr, a, gm, bt, wbf, out);
  } else {
    gat_fused<false><<<nblk, 256, 0, stream>>>(h, eb, Wl, Wr, a, gm, bt, nullptr, out);
  }
}